// Round 11
// baseline (205.111 us; speedup 1.0000x reference)
//
#include <hip/hip_runtime.h>
#include <hip/hip_bf16.h>

#define NB    8192
#define NEI   64
#define DIM   128
#define D2    256
#define NR_W  1001   // 2*CNT_R+1
#define NR_Z  1000   // 2*CNT_R
#define BPW   2      // b's per wave; grid = 8192/(8*BPW) = 512 blocks
#define C2L2E 2.8853900817779268f   // 2*log2(e): exp(2v) = exp2(C2L2E*v)

typedef __attribute__((ext_vector_type(8))) short bf16x8;   // 8 bf16 = 4 VGPR
typedef __attribute__((ext_vector_type(4))) float f32x4;

__device__ __forceinline__ ushort f2bf(float x) {
    union { float f; unsigned u; } c; c.f = x;
    unsigned u = c.u;
    return (ushort)((u + 0x7fffu + ((u >> 16) & 1u)) >> 16);   // RNE
}

__device__ __forceinline__ unsigned pk2(float a, float b) {
    __hip_bfloat162 h = __float22bfloat162_rn(make_float2(a, b));  // v_cvt_pk_bf16_f32
    return *(unsigned*)&h;
}

__device__ __forceinline__ bf16x8 mkbf(unsigned a, unsigned b, unsigned c, unsigned d) {
    union { uint4 u; bf16x8 v; } x; x.u = make_uint4(a, b, c, d); return x.v;
}

// ---------------- precompute kernels ----------------

__global__ void k_norm(const float* __restrict__ w_r_table, float* __restrict__ norm_t) {
    int r = blockIdx.x;          // 0..1000
    int t = threadIdx.x;         // 0..127
    float v = w_r_table[r * DIM + t];
    float s = v * v;
    #pragma unroll
    for (int m = 1; m < 64; m <<= 1) s += __shfl_xor(s, m);
    __shared__ float sh[2];
    if ((t & 63) == 0) sh[t >> 6] = s;
    __syncthreads();
    float tot = sh[0] + sh[1];
    norm_t[r * DIM + t] = v / sqrtf(tot);
}

// Tq[r][o] = attn_W_b[o] + sum_{k<128} attn_W_w[o][k] * zq_table[r][k]
__global__ void k_tq(const float* __restrict__ zq_table, const float* __restrict__ W,
                     const float* __restrict__ bias, float* __restrict__ tq_t) {
    int r = blockIdx.x;          // 0..999
    int o = threadIdx.x;         // 0..255
    __shared__ float4 z4[32];
    if (o < 32) z4[o] = ((const float4*)(zq_table + r * DIM))[o];
    __syncthreads();
    const float4* wr = (const float4*)(W + o * D2);
    float acc = bias[o];
    #pragma unroll 8
    for (int i = 0; i < 32; ++i) {
        float4 wv = wr[i], zv = z4[i];
        acc += wv.x*zv.x + wv.y*zv.y + wv.z*zv.z + wv.w*zv.w;
    }
    tq_t[r * D2 + o] = acc;
}

// B fragments in mfma_16x16x32_bf16 order (layout verified rounds 2-10):
// bfrag[((nt*4+kt)*64 + lane)*8 + j] = W2[k][o], o = nt*16+(lane&15), k = kt*32+(lane>>4)*8+j
__global__ void k_bfrag(const float* __restrict__ W, ushort* __restrict__ bfrag) {
    int nt = blockIdx.x;         // 0..15
    int kt = blockIdx.y;         // 0..3
    int l  = threadIdx.x;        // 0..63
    int o  = nt * 16 + (l & 15);
    int k  = kt * 32 + (l >> 4) * 8;
    const float4* src = (const float4*)(W + o * D2 + DIM + k);
    float4 a = src[0], c = src[1];
    uint4 w;
    w.x = f2bf(a.x) | ((unsigned)f2bf(a.y) << 16);
    w.y = f2bf(a.z) | ((unsigned)f2bf(a.w) << 16);
    w.z = f2bf(c.x) | ((unsigned)f2bf(c.y) << 16);
    w.w = f2bf(c.z) | ((unsigned)f2bf(c.w) << 16);
    *(uint4*)(bfrag + ((nt * 4 + kt) * 64 + l) * 8) = w;
}

// SUA = sum(u_a_w)  (alpha = SUA - 2*sum(ua*r))
__global__ void k_sua(const float* __restrict__ u, float* __restrict__ sua) {
    int t = threadIdx.x;         // 0..255
    float v = u[t];
    #pragma unroll
    for (int m = 1; m < 64; m <<= 1) v += __shfl_xor(v, m);
    __shared__ float sh[4];
    if ((t & 63) == 0) sh[t >> 6] = v;
    __syncthreads();
    if (t == 0) sua[0] = sh[0] + sh[1] + sh[2] + sh[3];
}

// ---------------- main fused kernel: ONE WAVE = ONE b, no per-b barriers ----
// W2 fragments staged once per block into 64 KB LDS (re-read per MFMA --
// nothing for the allocator to rematerialize). A-fragments are built in
// registers from projection math (compute-derived -> cannot be remat'd).
// Latency hiding is pure wave-slot TLP across 16 independent waves/CU.

__global__ __launch_bounds__(512, 4) void k_main(
    const float* __restrict__ e_emb,    // (B,64,128)
    const float* __restrict__ rw,       // (B,64)
    const int*   __restrict__ nei_rid,  // (B,64)
    const int*   __restrict__ q_rid,    // (B,)
    const float* __restrict__ norm_t,   // (1001,128)
    const float* __restrict__ tq_t,     // (1000,256)
    const ushort* __restrict__ bfrag,   // (16,4,64,8) bf16, tile-major
    const float* __restrict__ u_a_sum,  // scalar SUA
    const float* __restrict__ u_a_w,    // (256,)
    float* __restrict__ out)            // (B,64)
{
    __shared__ __align__(16) ushort w2l[16 * 4 * 64 * 8];   // 65536 B

    const int t    = threadIdx.x;
    const int wave = t >> 6, lane = t & 63;
    const int ln   = lane & 15, hi = lane >> 4;

    // ---- stage all W2 fragments to LDS (once per block) ----
    {
        const uint4* src = (const uint4*)bfrag;   // 4096 x 16B
        uint4* dst = (uint4*)w2l;
        #pragma unroll
        for (int i = 0; i < 8; ++i) dst[t + 512 * i] = src[t + 512 * i];
    }
    __syncthreads();   // only barrier in the kernel

    const float sua = u_a_sum[0];

    #pragma unroll 1
    for (int ib = 0; ib < BPW; ++ib) {
        const int b = (blockIdx.x * 8 + wave) * BPW + ib;

        // per-lane row rids (row = mt*16 + ln)
        int ridv[4];
        #pragma unroll
        for (int mt = 0; mt < 4; ++mt) ridv[mt] = nei_rid[b * NEI + mt * 16 + ln];
        const int qr = q_rid[b];

        // row base pointers (lane's k-slice starts at hi*8)
        const float* er[4];
        const float* nr[4];
        #pragma unroll
        for (int mt = 0; mt < 4; ++mt) {
            er[mt] = e_emb + ((size_t)b * NEI + mt * 16 + ln) * DIM + hi * 8;
            nr[mt] = norm_t + ridv[mt] * DIM + hi * 8;
        }

        // ---- phase A: d[mt] = full-row e . n (f32) ----
        float dacc[4] = {0.f, 0.f, 0.f, 0.f};
        #pragma unroll
        for (int kt = 0; kt < 4; ++kt)
            #pragma unroll
            for (int mt = 0; mt < 4; ++mt) {
                float4 e0 = ((const float4*)(er[mt] + kt * 32))[0];
                float4 e1 = ((const float4*)(er[mt] + kt * 32))[1];
                float4 n0 = ((const float4*)(nr[mt] + kt * 32))[0];
                float4 n1 = ((const float4*)(nr[mt] + kt * 32))[1];
                dacc[mt] += e0.x*n0.x + e0.y*n0.y + e0.z*n0.z + e0.w*n0.w
                          + e1.x*n1.x + e1.y*n1.y + e1.z*n1.z + e1.w*n1.w;
            }
        #pragma unroll
        for (int mt = 0; mt < 4; ++mt) {
            dacc[mt] += __shfl_xor(dacc[mt], 16);   // reduce across hi
            dacc[mt] += __shfl_xor(dacc[mt], 32);
        }

        // ---- phase B: reload (L2-hot), project, pack A-fragments ----
        bf16x8 A[4][4];
        #pragma unroll
        for (int kt = 0; kt < 4; ++kt)
            #pragma unroll
            for (int mt = 0; mt < 4; ++mt) {
                float4 e0 = ((const float4*)(er[mt] + kt * 32))[0];
                float4 e1 = ((const float4*)(er[mt] + kt * 32))[1];
                float4 n0 = ((const float4*)(nr[mt] + kt * 32))[0];
                float4 n1 = ((const float4*)(nr[mt] + kt * 32))[1];
                const float d = dacc[mt];
                float p0 = fmaf(-d, n0.x, e0.x), p1 = fmaf(-d, n0.y, e0.y);
                float p2 = fmaf(-d, n0.z, e0.z), p3 = fmaf(-d, n0.w, e0.w);
                float p4 = fmaf(-d, n1.x, e1.x), p5 = fmaf(-d, n1.y, e1.y);
                float p6 = fmaf(-d, n1.z, e1.z), p7 = fmaf(-d, n1.w, e1.w);
                A[mt][kt] = mkbf(pk2(p0,p1), pk2(p2,p3), pk2(p4,p5), pk2(p6,p7));
            }

        // ---- nt-loop: GEMM from LDS-B + fused tanh/ua epilogue ----
        float pr[4][4];
        #pragma unroll
        for (int mt = 0; mt < 4; ++mt)
            #pragma unroll
            for (int j = 0; j < 4; ++j) pr[mt][j] = 0.f;

        #pragma unroll 1
        for (int nt = 0; nt < 16; ++nt) {
            const float tql = C2L2E * tq_t[qr * D2 + nt * 16 + ln];
            const float ual = u_a_w[nt * 16 + ln];
            f32x4 acc[4];
            #pragma unroll
            for (int mt = 0; mt < 4; ++mt) acc[mt] = (f32x4){0.f,0.f,0.f,0.f};
            #pragma unroll
            for (int kt = 0; kt < 4; ++kt) {
                bf16x8 Bt = *(const bf16x8*)((const char*)w2l + (((nt*4 + kt)*64 + lane) << 4));
                #pragma unroll
                for (int mt = 0; mt < 4; ++mt)
                    acc[mt] = __builtin_amdgcn_mfma_f32_16x16x32_bf16(A[mt][kt], Bt, acc[mt], 0, 0, 0);
            }
            // C/D: col(o) = nt*16+ln, row = mt*16 + hi*4 + j
            #pragma unroll
            for (int mt = 0; mt < 4; ++mt)
                #pragma unroll
                for (int j = 0; j < 4; ++j) {
                    float ex = __builtin_exp2f(fmaf(C2L2E, acc[mt][j], tql));
                    float r  = __builtin_amdgcn_rcpf(ex + 1.f);
                    pr[mt][j] = fmaf(ual, r, pr[mt][j]);
                }
        }

        // ---- reduce ua-dot across the 16 ln lanes (DPP butterfly) ----
        #pragma unroll
        for (int m = 1; m < 16; m <<= 1)
            #pragma unroll
            for (int mt = 0; mt < 4; ++mt)
                #pragma unroll
                for (int j = 0; j < 4; ++j) pr[mt][j] += __shfl_xor(pr[mt][j], m);

        // ---- in-wave softmax: lane (ln,hi) owns row (ln>>2)*16 + hi*4 + (ln&3) ----
        float mya = 0.f;
        #pragma unroll
        for (int mt = 0; mt < 4; ++mt)
            #pragma unroll
            for (int j = 0; j < 4; ++j)
                if (ln == mt * 4 + j) mya = pr[mt][j];      // compile-time indices
        float alpha = fmaf(-2.f, mya, sua);                  // shift-invariant logit
        float myex = __expf(alpha);
        float s = myex;
        #pragma unroll
        for (int m = 1; m < 64; m <<= 1) s += __shfl_xor(s, m);   // rows bijective over 64 lanes
        const int row = ((ln >> 2) * 16) + (hi * 4) + (ln & 3);
        const float rwv = rw[(size_t)b * NEI + row];
        out[(size_t)b * NEI + row] = fmaf(myex, __builtin_amdgcn_rcpf(s), rwv);
    }
}

// ---------------- launch ----------------

extern "C" void kernel_launch(void* const* d_in, const int* in_sizes, int n_in,
                              void* d_out, int out_size, void* d_ws, size_t ws_size,
                              hipStream_t stream) {
    const float* e_emb   = (const float*)d_in[0];
    const float* rw      = (const float*)d_in[1];
    const float* w_r_tab = (const float*)d_in[2];
    const float* zq_tab  = (const float*)d_in[3];
    const float* attn_W  = (const float*)d_in[4];
    const float* attn_b  = (const float*)d_in[5];
    const float* u_a_w   = (const float*)d_in[6];
    // d_in[7] = u_a_b: cancels in softmax, unused
    const int*   nei_rid = (const int*)d_in[8];
    const int*   q_rid   = (const int*)d_in[9];
    float* out = (float*)d_out;

    float* ws = (float*)d_ws;
    float* norm_t = ws;                             // 1001*128 f32
    float* tq_t   = norm_t + NR_W * DIM;            // 1000*256 f32
    ushort* bfrag = (ushort*)(tq_t + NR_Z * D2);    // 16*4*64*8 bf16
    float* suap   = (float*)(bfrag + 16*4*64*8);    // 1 f32

    k_norm<<<NR_W, DIM, 0, stream>>>(w_r_tab, norm_t);
    k_tq<<<NR_Z, D2, 0, stream>>>(zq_tab, attn_W, attn_b, tq_t);
    k_bfrag<<<dim3(16, 4), 64, 0, stream>>>(attn_W, bfrag);
    k_sua<<<1, 256, 0, stream>>>(u_a_w, suap);
    k_main<<<NB / (8 * BPW), 512, 0, stream>>>(e_emb, rw, nei_rid, q_rid,
                                               norm_t, tq_t, bfrag, suap, u_a_w, out);
}

// Round 12
// 181.810 us; speedup vs baseline: 1.1282x; 1.1282x over previous
//
#include <hip/hip_runtime.h>
#include <hip/hip_bf16.h>

#define NB    8192
#define NEI   64
#define DIM   128
#define D2    256
#define NR_W  1001   // 2*CNT_R+1
#define NR_Z  1000   // 2*CNT_R
#define EPB_LD 136   // bf16 elems per LDS row (128 + 8 pad)
#define BPB   8      // b's per block; grid = 1024
#define C2L2E 2.8853900817779268f   // 2*log2(e): exp(2v) = exp2(C2L2E*v)

typedef __attribute__((ext_vector_type(8))) short bf16x8;   // 8 bf16 = 4 VGPR
typedef __attribute__((ext_vector_type(4))) float f32x4;
typedef __attribute__((ext_vector_type(4))) unsigned int u32x4;

// opaque 16B load (pre-loop only: B-fragments). Bound by loop-top vmcnt(0).
#define GLOAD16(dst, addr, OFF) \
    asm volatile("global_load_dwordx4 %0, %1, off offset:" OFF \
                 : "=v"(dst) : "v"(addr))

__device__ __forceinline__ ushort f2bf(float x) {
    union { float f; unsigned u; } c; c.f = x;
    unsigned u = c.u;
    return (ushort)((u + 0x7fffu + ((u >> 16) & 1u)) >> 16);   // RNE
}

__device__ __forceinline__ unsigned pk2(float a, float b) {
    __hip_bfloat162 h = __float22bfloat162_rn(make_float2(a, b));  // v_cvt_pk_bf16_f32
    return *(unsigned*)&h;
}

__device__ __forceinline__ bf16x8 asbf(u32x4 v) {
    union { u32x4 a; bf16x8 b; } u; u.a = v; return u.b;
}

// visible async global->LDS (counted correctly by the compiler's vmcnt model)
__device__ __forceinline__ void gll16(const void* g, void* l) {
    __builtin_amdgcn_global_load_lds(
        (const __attribute__((address_space(1))) unsigned int*)g,
        (__attribute__((address_space(3))) unsigned int*)l, 16, 0, 0);
}

// ---------------- precompute kernels ----------------

__global__ void k_norm(const float* __restrict__ w_r_table, float* __restrict__ norm_t) {
    int r = blockIdx.x;          // 0..1000
    int t = threadIdx.x;         // 0..127
    float v = w_r_table[r * DIM + t];
    float s = v * v;
    #pragma unroll
    for (int m = 1; m < 64; m <<= 1) s += __shfl_xor(s, m);
    __shared__ float sh[2];
    if ((t & 63) == 0) sh[t >> 6] = s;
    __syncthreads();
    float tot = sh[0] + sh[1];
    norm_t[r * DIM + t] = v / sqrtf(tot);
}

// Tq[r][o] = attn_W_b[o] + sum_{k<128} attn_W_w[o][k] * zq_table[r][k]
__global__ void k_tq(const float* __restrict__ zq_table, const float* __restrict__ W,
                     const float* __restrict__ bias, float* __restrict__ tq_t) {
    int r = blockIdx.x;          // 0..999
    int o = threadIdx.x;         // 0..255
    __shared__ float4 z4[32];
    if (o < 32) z4[o] = ((const float4*)(zq_table + r * DIM))[o];
    __syncthreads();
    const float4* wr = (const float4*)(W + o * D2);
    float acc = bias[o];
    #pragma unroll 8
    for (int i = 0; i < 32; ++i) {
        float4 wv = wr[i], zv = z4[i];
        acc += wv.x*zv.x + wv.y*zv.y + wv.z*zv.z + wv.w*zv.w;
    }
    tq_t[r * D2 + o] = acc;
}

// dense per-b Tq gather, pre-scaled by 2*log2(e): kills the qr->tq serial
// dependent-load chain inside the hot loop.
__global__ void k_tqd(const float* __restrict__ tq_t, const int* __restrict__ q_rid,
                      float* __restrict__ tqd) {
    int b = blockIdx.x;          // 0..8191
    int o = threadIdx.x;         // 0..255
    tqd[(size_t)b * D2 + o] = C2L2E * tq_t[q_rid[b] * D2 + o];
}

// B fragments in mfma_16x16x32_bf16 order (layout verified rounds 2-11):
// bfrag[((ot*4+kt)*64 + lane)*8 + j] = W2[k][o], o = ot*16+(lane&15), k = kt*32+(lane>>4)*8+j
__global__ void k_bfrag(const float* __restrict__ W, ushort* __restrict__ bfrag) {
    int ot = blockIdx.x;         // 0..15
    int kt = blockIdx.y;         // 0..3
    int l  = threadIdx.x;        // 0..63
    int o  = ot * 16 + (l & 15);
    int k  = kt * 32 + (l >> 4) * 8;
    const float4* src = (const float4*)(W + o * D2 + DIM + k);
    float4 a = src[0], c = src[1];
    uint4 w;
    w.x = f2bf(a.x) | ((unsigned)f2bf(a.y) << 16);
    w.y = f2bf(a.z) | ((unsigned)f2bf(a.w) << 16);
    w.z = f2bf(c.x) | ((unsigned)f2bf(c.y) << 16);
    w.w = f2bf(c.z) | ((unsigned)f2bf(c.w) << 16);
    *(uint4*)(bfrag + ((ot * 4 + kt) * 64 + l) * 8) = w;
}

// SUA = sum(u_a_w)  (alpha = SUA - 2*sum(ua*r))
__global__ void k_sua(const float* __restrict__ u, float* __restrict__ sua) {
    int t = threadIdx.x;         // 0..255
    float v = u[t];
    #pragma unroll
    for (int m = 1; m < 64; m <<= 1) v += __shfl_xor(v, m);
    __shared__ float sh[4];
    if ((t & 63) == 0) sh[t >> 6] = v;
    __syncthreads();
    if (t == 0) sua[0] = sh[0] + sh[1] + sh[2] + sh[3];
}

// ---------------- main fused kernel ----------------
// 512 thr / 8 waves, BPB b's per block, 3 blocks/CU (52 KB LDS).
// e-stream: global_load_lds (compiler-visible, counted) into a single
// 32 KB LDS buffer; staged for b+1 during b's MFMA phase. Barriers are raw
// s_barrier + lgkmcnt(0) -- vmcnt is NEVER drained mid-loop except the
// per-wave vmcnt(0) at loop top that binds the arrived stage. All scalar
// prefetches are issued BEFORE the gll calls so compiler wait points
// cannot drain the staging queue.

__global__ __launch_bounds__(512, 2) void k_main(
    const float* __restrict__ e_emb,    // (B,64,128)
    const float* __restrict__ rw,       // (B,64)
    const int*   __restrict__ nei_rid,  // (B,64)
    const float* __restrict__ norm_t,   // (1001,128)
    const float* __restrict__ tqd,      // (B,256) pre-scaled
    const ushort* __restrict__ bfrag,   // (16,4,64,8) bf16
    const float* __restrict__ u_a_sum,  // scalar SUA
    const float* __restrict__ u_a_w,    // (256,)
    float* __restrict__ out)            // (B,64)
{
    __shared__ __align__(16) float  e_raw[NEI * DIM];    // 32768 B (swizzled src)
    __shared__ __align__(16) ushort ep16[NEI * EPB_LD];  // 17408 B
    __shared__ float alpw[8][NEI];                       // 2048 B

    const int t    = threadIdx.x;
    const int wave = t >> 6, lane = t & 63;
    const int ln   = lane & 15, hi = lane >> 4;
    const int row  = t >> 3, q3 = t & 7;                 // proj: 8 lanes/row
    const int b0   = blockIdx.x * BPB;

    // ---- opaque B-fragment loads (pre-loop; bound at first loop-top) ----
    const char* bb0 = (const char*)bfrag + (((wave * 2) * 4 * 64) + lane) * 16;
    const char* bb1 = bb0 + 4096;
    u32x4 bq0, bq1, bq2, bq3, bq4, bq5, bq6, bq7;
    GLOAD16(bq0, bb0, "0");    GLOAD16(bq1, bb0, "1024");
    GLOAD16(bq2, bb0, "2048"); GLOAD16(bq3, bb0, "3072");
    GLOAD16(bq4, bb1, "0");    GLOAD16(bq5, bb1, "1024");
    GLOAD16(bq6, bb1, "2048"); GLOAD16(bq7, bb1, "3072");

    const float ua0 = u_a_w[wave * 32 + ln];
    const float ua1 = u_a_w[wave * 32 + 16 + ln];
    const float sua = u_a_sum[0];

    // ---- swizzled gll SOURCE offsets (LDS dest linear; read side XORs) ----
    unsigned soff[4];
    #pragma unroll
    for (int c = 0; c < 4; ++c) {
        unsigned D = (unsigned)(wave*4096 + c*1024 + lane*16);
        unsigned r7 = (D >> 9) & 7;
        soff[c] = D ^ (r7 << 4);
    }
    const char* ebase = (const char*)e_emb;

    // ---- prologue: norm rows + scalars for b0, rid for b0+1, stage e(b0) ----
    int ridn;                       // rid for the NEXT b (addresses formed in step4)
    float4 nv0, nv1, nv2, nv3;      // this b's norm row slice (q3*16 .. +15)
    {
        int ridc = nei_rid[b0 * NEI + row];
        const float4* np = (const float4*)(norm_t + ridc * DIM + q3 * 16);
        nv0 = np[0]; nv1 = np[1]; nv2 = np[2]; nv3 = np[3];
        ridn = (BPB > 1) ? nei_rid[(b0 + 1) * NEI + row] : 0;
    }
    float tqc0 = tqd[(size_t)b0 * D2 + wave * 32 + ln];
    float tqc1 = tqd[(size_t)b0 * D2 + wave * 32 + 16 + ln];
    float rwc  = rw[(size_t)b0 * NEI + (t & 63)];
    float tqn0 = 0.f, tqn1 = 0.f, rwn = 0.f;
    #pragma unroll
    for (int c = 0; c < 4; ++c)
        gll16(ebase + (((size_t)b0) << 15) + soff[c], (char*)e_raw + wave*4096 + c*1024);

    #pragma unroll 1
    for (int i = 0; i < BPB; ++i) {
        const int b = b0 + i;

        // ---- step1: own-wave vmem drain (stage+scalars arrived) + barrier ----
        asm volatile("s_waitcnt vmcnt(0)" ::: "memory");
        __builtin_amdgcn_sched_barrier(0);
        __builtin_amdgcn_s_barrier();
        __builtin_amdgcn_sched_barrier(0);

        // ---- step2: projection from LDS e + resident norm regs ----
        {
            const unsigned rbase = (unsigned)(row * 512 + q3 * 64);
            const unsigned rx = (unsigned)((row & 7) << 4);
            float4 e0 = *(const float4*)((const char*)e_raw + ((rbase +  0) ^ rx));
            float4 e1 = *(const float4*)((const char*)e_raw + ((rbase + 16) ^ rx));
            float4 e2 = *(const float4*)((const char*)e_raw + ((rbase + 32) ^ rx));
            float4 e3 = *(const float4*)((const char*)e_raw + ((rbase + 48) ^ rx));
            float part = e0.x*nv0.x + e0.y*nv0.y + e0.z*nv0.z + e0.w*nv0.w
                       + e1.x*nv1.x + e1.y*nv1.y + e1.z*nv1.z + e1.w*nv1.w
                       + e2.x*nv2.x + e2.y*nv2.y + e2.z*nv2.z + e2.w*nv2.w
                       + e3.x*nv3.x + e3.y*nv3.y + e3.z*nv3.z + e3.w*nv3.w;
            part += __shfl_xor(part, 1);
            part += __shfl_xor(part, 2);
            part += __shfl_xor(part, 4);
            const float d = part;                 // full-row e . n
            float p0 = fmaf(-d, nv0.x, e0.x), p1 = fmaf(-d, nv0.y, e0.y);
            float p2 = fmaf(-d, nv0.z, e0.z), p3 = fmaf(-d, nv0.w, e0.w);
            float p4 = fmaf(-d, nv1.x, e1.x), p5 = fmaf(-d, nv1.y, e1.y);
            float p6 = fmaf(-d, nv1.z, e1.z), p7 = fmaf(-d, nv1.w, e1.w);
            uint4 w0; w0.x = pk2(p0,p1); w0.y = pk2(p2,p3); w0.z = pk2(p4,p5); w0.w = pk2(p6,p7);
            float s0 = fmaf(-d, nv2.x, e2.x), s1 = fmaf(-d, nv2.y, e2.y);
            float s2 = fmaf(-d, nv2.z, e2.z), s3 = fmaf(-d, nv2.w, e2.w);
            float s4 = fmaf(-d, nv3.x, e3.x), s5 = fmaf(-d, nv3.y, e3.y);
            float s6 = fmaf(-d, nv3.z, e3.z), s7 = fmaf(-d, nv3.w, e3.w);
            uint4 w1; w1.x = pk2(s0,s1); w1.y = pk2(s2,s3); w1.z = pk2(s4,s5); w1.w = pk2(s6,s7);
            char* dst = (char*)ep16 + row * (EPB_LD*2) + q3 * 32;
            *(uint4*)dst = w0;
            *(uint4*)(dst + 16) = w1;
        }

        // ---- step3: LDS fence + barrier (NO vmcnt drain) ----
        asm volatile("s_waitcnt lgkmcnt(0)" ::: "memory");
        __builtin_amdgcn_s_barrier();
        __builtin_amdgcn_sched_barrier(0);

        // ---- step4: prefetch b+1 (scalars FIRST, then gll; pinned here) ----
        if (i + 1 < BPB) {
            const float4* np = (const float4*)(norm_t + ridn * DIM + q3 * 16);
            nv0 = np[0]; nv1 = np[1]; nv2 = np[2]; nv3 = np[3];
            if (i + 2 < BPB) ridn = nei_rid[(b + 2) * NEI + row];
            tqn0 = tqd[(size_t)(b + 1) * D2 + wave * 32 + ln];
            tqn1 = tqd[(size_t)(b + 1) * D2 + wave * 32 + 16 + ln];
            rwn  = rw[(size_t)(b + 1) * NEI + (t & 63)];
            #pragma unroll
            for (int c = 0; c < 4; ++c)
                gll16(ebase + (((size_t)(b + 1)) << 15) + soff[c],
                      (char*)e_raw + wave*4096 + c*1024);
        }
        __builtin_amdgcn_sched_barrier(0);

        // ---- step5: MFMA + fused epilogue per M-tile (wave owns 32 cols) ----
        #pragma unroll
        for (int mt = 0; mt < 4; ++mt) {
            bf16x8 a_[4];
            #pragma unroll
            for (int kt = 0; kt < 4; ++kt)
                a_[kt] = *(const bf16x8*)&ep16[(mt*16 + ln) * EPB_LD + kt*32 + hi*8];
            f32x4 acc0 = (f32x4){0.f,0.f,0.f,0.f}, acc1 = (f32x4){0.f,0.f,0.f,0.f};
            acc0 = __builtin_amdgcn_mfma_f32_16x16x32_bf16(a_[0], asbf(bq0), acc0, 0, 0, 0);
            acc1 = __builtin_amdgcn_mfma_f32_16x16x32_bf16(a_[0], asbf(bq4), acc1, 0, 0, 0);
            acc0 = __builtin_amdgcn_mfma_f32_16x16x32_bf16(a_[1], asbf(bq1), acc0, 0, 0, 0);
            acc1 = __builtin_amdgcn_mfma_f32_16x16x32_bf16(a_[1], asbf(bq5), acc1, 0, 0, 0);
            acc0 = __builtin_amdgcn_mfma_f32_16x16x32_bf16(a_[2], asbf(bq2), acc0, 0, 0, 0);
            acc1 = __builtin_amdgcn_mfma_f32_16x16x32_bf16(a_[2], asbf(bq6), acc1, 0, 0, 0);
            acc0 = __builtin_amdgcn_mfma_f32_16x16x32_bf16(a_[3], asbf(bq3), acc0, 0, 0, 0);
            acc1 = __builtin_amdgcn_mfma_f32_16x16x32_bf16(a_[3], asbf(bq7), acc1, 0, 0, 0);
            // C/D: col(=o) = ln, row(=neighbor) = mt*16 + hi*4 + j
            float pr[4];
            #pragma unroll
            for (int j = 0; j < 4; ++j) {
                float ex0 = __builtin_exp2f(fmaf(C2L2E, acc0[j], tqc0));
                float ex1 = __builtin_exp2f(fmaf(C2L2E, acc1[j], tqc1));
                float r0  = __builtin_amdgcn_rcpf(ex0 + 1.f);
                float r1  = __builtin_amdgcn_rcpf(ex1 + 1.f);
                pr[j] = fmaf(ua0, r0, ua1 * r1);
            }
            #pragma unroll
            for (int m = 1; m < 16; m <<= 1)            // xor 1/2/4/8 -> DPP
                #pragma unroll
                for (int j = 0; j < 4; ++j) pr[j] += __shfl_xor(pr[j], m);
            if (ln == 0) {
                #pragma unroll
                for (int j = 0; j < 4; ++j) alpw[wave][mt*16 + hi*4 + j] = pr[j];
            }
        }

        // ---- step6: LDS fence + barrier (NO vmcnt drain) ----
        asm volatile("s_waitcnt lgkmcnt(0)" ::: "memory");
        __builtin_amdgcn_s_barrier();
        __builtin_amdgcn_sched_barrier(0);

        // ---- step7: softmax + rw (shift-invariant) ----
        if (t < NEI) {
            float s8 = 0.f;
            #pragma unroll
            for (int w = 0; w < 8; ++w) s8 += alpw[w][t];
            float a = fmaf(-2.f, s8, sua);
            float p = __expf(a);
            float s = p;
            #pragma unroll
            for (int m = 1; m < 64; m <<= 1) s += __shfl_xor(s, m);
            out[(size_t)b * NEI + t] = fmaf(p, __builtin_amdgcn_rcpf(s), rwc);
        }

        // ---- rotate prefetched scalars ----
        if (i + 1 < BPB) { tqc0 = tqn0; tqc1 = tqn1; rwc = rwn; }
        // Hazard audit: e_raw gll(b+1) issued at step4 AFTER step3's barrier
        // (all waves done reading e_raw(b)); consumed after step1(i+1)'s
        // per-wave vmcnt(0)+barrier. ep16 written step2, read step5, re-written
        // after step1(i+1). alpw written step5, read step7, re-written after
        // step3(i+1). All separated by barriers.
    }
}

// ---------------- launch ----------------

extern "C" void kernel_launch(void* const* d_in, const int* in_sizes, int n_in,
                              void* d_out, int out_size, void* d_ws, size_t ws_size,
                              hipStream_t stream) {
    const float* e_emb   = (const float*)d_in[0];
    const float* rw      = (const float*)d_in[1];
    const float* w_r_tab = (const float*)d_in[2];
    const float* zq_tab  = (const float*)d_in[3];
    const float* attn_W  = (const float*)d_in[4];
    const float* attn_b  = (const float*)d_in[5];
    const float* u_a_w   = (const float*)d_in[6];
    // d_in[7] = u_a_b: cancels in softmax, unused
    const int*   nei_rid = (const int*)d_in[8];
    const int*   q_rid   = (const int*)d_in[9];
    float* out = (float*)d_out;

    float* ws = (float*)d_ws;
    float* norm_t = ws;                             // 1001*128 f32
    float* tq_t   = norm_t + NR_W * DIM;            // 1000*256 f32
    ushort* bfrag = (ushort*)(tq_t + NR_Z * D2);    // 16*4*64*8 bf16
    float* suap   = (float*)(bfrag + 16*4*64*8);    // 1 f32
    float* tqd    = suap + 4;                       // 8192*256 f32 (8 MB)

    k_norm<<<NR_W, DIM, 0, stream>>>(w_r_tab, norm_t);
    k_tq<<<NR_Z, D2, 0, stream>>>(zq_tab, attn_W, attn_b, tq_t);
    k_tqd<<<NB, D2, 0, stream>>>(tq_t, q_rid, tqd);
    k_bfrag<<<dim3(16, 4), 64, 0, stream>>>(attn_W, bfrag);
    k_sua<<<1, 256, 0, stream>>>(u_a_w, suap);
    k_main<<<NB / BPB, 512, 0, stream>>>(e_emb, rw, nei_rid,
                                         norm_t, tqd, bfrag, suap, u_a_w, out);
}